// Round 3
// baseline (692.327 us; speedup 1.0000x reference)
//
#include <hip/hip_runtime.h>
#include <stdint.h>

#define SQ   2048
#define DIN  4096
#define NH   32
#define NKV  8
#define HD   128
#define NQKV 6144

typedef float f32x4 __attribute__((ext_vector_type(4)));
typedef short bf16x8 __attribute__((ext_vector_type(8)));

__device__ __forceinline__ short f2bf(float f) {
  union { float f; uint32_t u; } v; v.f = f;
  uint32_t r = (v.u + 0x7FFFu + ((v.u >> 16) & 1u)) >> 16;
  return (short)r;
}

// async global -> LDS, 16 bytes per lane, dst = lds_base + lane*16 (HW-fixed)
__device__ __forceinline__ void gl2lds(const void* g, void* l) {
  __builtin_amdgcn_global_load_lds(
      (const __attribute__((address_space(1))) void*)g,
      (__attribute__((address_space(3))) void*)l, 16, 0, 0);
}

// ---------------- fp32 -> bf16 elementwise convert ----------------
__global__ void cvt_bf16(const float* __restrict__ src, short* __restrict__ dst, long n) {
  long i = ((long)blockIdx.x * blockDim.x + threadIdx.x) * 4;
  if (i + 3 < n) {
    float4 v = *(const float4*)(src + i);
    short o[4] = { f2bf(v.x), f2bf(v.y), f2bf(v.z), f2bf(v.w) };
    *(uint2*)(dst + i) = *(uint2*)o;
  }
}

// ---------------- tiled transpose + convert (weights) ----------------
__global__ __launch_bounds__(256) void transpose_cvt(const float* __restrict__ src, int ldS, long zS,
                                                     short* __restrict__ dst, int ldD, long zD) {
  __shared__ float tile[64][65];
  src += (long)blockIdx.z * zS;
  dst += (long)blockIdx.z * zD;
  int r0 = blockIdx.y * 64, c0 = blockIdx.x * 64;
  int tid = threadIdx.x;
#pragma unroll
  for (int i = 0; i < 16; ++i) {
    int idx = i * 256 + tid;
    int rr = idx >> 6, cc = idx & 63;
    tile[rr][cc] = src[(long)(r0 + rr) * ldS + c0 + cc];
  }
  __syncthreads();
#pragma unroll
  for (int i = 0; i < 16; ++i) {
    int idx = i * 256 + tid;
    int dr = idx >> 6, dc = idx & 63;
    dst[(long)(c0 + dr) * ldD + r0 + dc] = f2bf(tile[dc][dr]);
  }
}

#define BM 128
#define BN 128
#define BK 32

// ---------------- QKV GEMM with fused LN+RoPE / V-transpose epilogue ----------------
// Wave layout 2x8: wave w owns rows w*32..+31, ALL 128 cols -> LN + RoPE are intra-lane/
// intra-l16-group. Column block cb: <32 q head, 32..39 k group, 40..47 v group.
__global__ __launch_bounds__(256) void gemm_qkv(const short* __restrict__ A, const short* __restrict__ Bt,
                                                const float* __restrict__ cosb, const float* __restrict__ sinb,
                                                const float* __restrict__ qw, const float* __restrict__ qb,
                                                const float* __restrict__ kw, const float* __restrict__ kb,
                                                short* __restrict__ qo, short* __restrict__ ko,
                                                short* __restrict__ vo) {
  __shared__ __align__(16) short smem[8704];   // As[4096] | Bs[4096]; vbuf[64][136] aliases
  short* As = smem;
  short* Bs = smem + 4096;
  const int K = DIN;
  int tid = threadIdx.x, wave = tid >> 6, lane = tid & 63;
  int l16 = lane & 15, lq = lane >> 4;
  int m0 = blockIdx.y * BM;
  int cb = blockIdx.x;
  long n0 = (long)cb * BN;
  int wm = wave * 32;
  int ch = (lane & 3) ^ ((lane >> 3) & 3);
  f32x4 acc[2][8] = {};
  for (int k0 = 0; k0 < K; k0 += BK) {
#pragma unroll
    for (int c = 0; c < 2; ++c) {
      int call = wave * 2 + c;
      int r = call * 16 + (lane >> 2);
      gl2lds(&A[(long)(m0 + r) * K + k0 + ch * 8], &As[call * 512]);
      gl2lds(&Bt[(n0 + r) * K + k0 + ch * 8], &Bs[call * 512]);
    }
    __syncthreads();
    bf16x8 af[2], bfr[8];
#pragma unroll
    for (int i = 0; i < 2; ++i) {
      int row = wm + i * 16 + l16;
      af[i] = *(const bf16x8*)&As[row * BK + (lq ^ ((row >> 1) & 3)) * 8];
    }
#pragma unroll
    for (int j = 0; j < 8; ++j) {
      int row = j * 16 + l16;
      bfr[j] = *(const bf16x8*)&Bs[row * BK + (lq ^ ((row >> 1) & 3)) * 8];
    }
#pragma unroll
    for (int i = 0; i < 2; ++i)
#pragma unroll
      for (int j = 0; j < 8; ++j)
        acc[i][j] = __builtin_amdgcn_mfma_f32_16x16x32_bf16(af[i], bfr[j], acc[i][j], 0, 0, 0);
    __syncthreads();
  }
  if (cb < 40) {
    // ---- fused LayerNorm + RoPE, write q (h,s,d) / k (g,s,d) bf16 ----
    bool isq = cb < NH;
    const float* lw = isq ? qw : kw;
    const float* lb = isq ? qb : kb;
    float wv[8], bv[8];
#pragma unroll
    for (int j = 0; j < 8; ++j) { wv[j] = lw[j * 16 + l16]; bv[j] = lb[j * 16 + l16]; }
    short* dst = isq ? (qo + (long)cb * SQ * HD) : (ko + (long)(cb - 32) * SQ * HD);
#pragma unroll
    for (int i = 0; i < 2; ++i)
#pragma unroll
      for (int r = 0; r < 4; ++r) {
        int s = m0 + wm + i * 16 + lq * 4 + r;
        float s1 = 0.f, s2 = 0.f;
#pragma unroll
        for (int j = 0; j < 8; ++j) { float v = acc[i][j][r]; s1 += v; s2 += v * v; }
#pragma unroll
        for (int o = 1; o < 16; o <<= 1) { s1 += __shfl_xor(s1, o); s2 += __shfl_xor(s2, o); }
        float mu = s1 * (1.f / 128.f);
        float rstd = rsqrtf(s2 * (1.f / 128.f) - mu * mu + 1e-6f);
        float val[8];
#pragma unroll
        for (int j = 0; j < 8; ++j) val[j] = (acc[i][j][r] - mu) * rstd * wv[j] + bv[j];
#pragma unroll
        for (int j = 0; j < 4; ++j) {
          int d = j * 16 + l16;
          float c = cosb[(long)s * HD + d];     // cos[s][d] == cos[s][d+64]
          float sn = sinb[(long)s * HD + d];
          dst[(long)s * HD + d]      = f2bf(val[j] * c - val[j + 4] * sn);
          dst[(long)s * HD + d + 64] = f2bf(val[j + 4] * c + val[j] * sn);
        }
      }
  } else {
    // ---- V: transpose via LDS, write (g, d, s) bf16, coalesced 16B stores ----
    short* vdst = vo + (long)(cb - 40) * HD * SQ;
#pragma unroll
    for (int p = 0; p < 2; ++p) {
      __syncthreads();
#pragma unroll
      for (int i = 0; i < 2; ++i)
#pragma unroll
        for (int j = 0; j < 4; ++j) {
          int dl = j * 16 + l16;
#pragma unroll
          for (int r = 0; r < 4; ++r) {
            int sl = wm + i * 16 + lq * 4 + r;
            smem[dl * 136 + sl] = f2bf(acc[i][p * 4 + j][r]);
          }
        }
      __syncthreads();
#pragma unroll
      for (int c = 0; c < 4; ++c) {
        int idx = c * 256 + tid;
        int drow = idx >> 4, off = (idx & 15) * 8;
        uint4 v = *(const uint4*)&smem[drow * 136 + off];
        *(uint4*)&vdst[(long)(p * 64 + drow) * SQ + m0 + off] = v;
      }
    }
  }
}

// ---------------- plain GEMM for out-projection ----------------
__global__ __launch_bounds__(256) void gemm_bf16(const short* __restrict__ A, const short* __restrict__ Bt,
                                                 float* __restrict__ C, int M, int N, int K) {
  __shared__ __align__(16) short As[BM * BK];
  __shared__ __align__(16) short Bs[BN * BK];
  int tid = threadIdx.x;
  int wave = tid >> 6, lane = tid & 63;
  int l16 = lane & 15, lq = lane >> 4;
  int m0 = blockIdx.y * BM, n0 = blockIdx.x * BN;
  int wm = (wave >> 1) * 64, wn = (wave & 1) * 64;
  int ch = (lane & 3) ^ ((lane >> 3) & 3);
  f32x4 acc[4][4] = {};
  for (int k0 = 0; k0 < K; k0 += BK) {
#pragma unroll
    for (int c = 0; c < 2; ++c) {
      int call = wave * 2 + c;
      int r = call * 16 + (lane >> 2);
      gl2lds(&A[(long)(m0 + r) * K + k0 + ch * 8], &As[call * 512]);
      gl2lds(&Bt[(long)(n0 + r) * K + k0 + ch * 8], &Bs[call * 512]);
    }
    __syncthreads();
    bf16x8 af[4], bfr[4];
#pragma unroll
    for (int i = 0; i < 4; ++i) {
      int row = wm + i * 16 + l16;
      af[i] = *(const bf16x8*)&As[row * BK + (lq ^ ((row >> 1) & 3)) * 8];
    }
#pragma unroll
    for (int j = 0; j < 4; ++j) {
      int row = wn + j * 16 + l16;
      bfr[j] = *(const bf16x8*)&Bs[row * BK + (lq ^ ((row >> 1) & 3)) * 8];
    }
#pragma unroll
    for (int i = 0; i < 4; ++i)
#pragma unroll
      for (int j = 0; j < 4; ++j)
        acc[i][j] = __builtin_amdgcn_mfma_f32_16x16x32_bf16(af[i], bfr[j], acc[i][j], 0, 0, 0);
    __syncthreads();
  }
#pragma unroll
  for (int i = 0; i < 4; ++i)
#pragma unroll
    for (int j = 0; j < 4; ++j)
#pragma unroll
      for (int r = 0; r < 4; ++r) {
        int row = m0 + wm + i * 16 + lq * 4 + r;
        int col = n0 + wn + j * 16 + l16;
        C[(long)row * N + col] = acc[i][j][r];
      }
}

// ---------------- flash attention: 128-key tiles, paired q-tiles share staging ----------------
#define NEG_INF (-__builtin_inff())

template<int NB, bool MASK>
__device__ __forceinline__ void score_tile(const short* Ks, const bf16x8* aq,
                                           float* p, float* m, float* l, f32x4* acc,
                                           int key0, int qrow0, int l16, int lq, float sc) {
  f32x4 s4[NB];
#pragma unroll
  for (int b = 0; b < NB; ++b) {
    f32x4 t = {0.f, 0.f, 0.f, 0.f};
#pragma unroll
    for (int kk = 0; kk < 4; ++kk) {
      bf16x8 bk = *(const bf16x8*)&Ks[(b * 16 + l16) * 128 + (((kk * 4 + lq) ^ l16) * 8)];
      t = __builtin_amdgcn_mfma_f32_16x16x32_bf16(aq[kk], bk, t, 0, 0, 0);
    }
    if (MASK) {
      int key = key0 + b * 16 + l16;
#pragma unroll
      for (int r = 0; r < 4; ++r) t[r] = (key > qrow0 + r) ? NEG_INF : t[r] * sc;
    } else {
#pragma unroll
      for (int r = 0; r < 4; ++r) t[r] = t[r] * sc;
    }
    s4[b] = t;
  }
#pragma unroll
  for (int r = 0; r < 4; ++r) {
    float mx = s4[0][r];
#pragma unroll
    for (int b = 1; b < NB; ++b) mx = fmaxf(mx, s4[b][r]);
#pragma unroll
    for (int o = 1; o < 16; o <<= 1) mx = fmaxf(mx, __shfl_xor(mx, o));
    float mnew = fmaxf(m[r], mx);
    float alpha = exp2f(m[r] - mnew);
    float sum = 0.f;
#pragma unroll
    for (int b = 0; b < NB; ++b) { float pv = exp2f(s4[b][r] - mnew); p[b * 4 + r] = pv; sum += pv; }
#pragma unroll
    for (int o = 1; o < 16; o <<= 1) sum += __shfl_xor(sum, o);
    l[r] = l[r] * alpha + sum;
    m[r] = mnew;
#pragma unroll
    for (int n = 0; n < 8; ++n) acc[n][r] *= alpha;
  }
}

template<int NB>
__device__ __forceinline__ void pv_tile(short* pbuf, const short* Vs, const float* p,
                                        f32x4* acc, int l16, int lq) {
#pragma unroll
  for (int b = 0; b < NB; ++b)
#pragma unroll
    for (int r = 0; r < 4; ++r)
      pbuf[(lq * 4 + r) * 136 + b * 16 + l16] = f2bf(p[b * 4 + r]);
#pragma unroll
  for (int kk = 0; kk < NB / 2; ++kk) {
    bf16x8 pf = *(const bf16x8*)&pbuf[l16 * 136 + kk * 32 + lq * 8];
#pragma unroll
    for (int n = 0; n < 8; ++n) {
      bf16x8 vf = *(const bf16x8*)&Vs[(n * 16 + l16) * 128 + (((kk * 4 + lq) ^ l16) * 8)];
      acc[n] = __builtin_amdgcn_mfma_f32_16x16x32_bf16(pf, vf, acc[n], 0, 0, 0);
    }
  }
}

__global__ __launch_bounds__(256, 2) void attn(const short* __restrict__ q, const short* __restrict__ k,
                                               const short* __restrict__ vT, short* __restrict__ ctx) {
  int pair = blockIdx.x, h = blockIdx.y, g = h >> 2;
  int tid = threadIdx.x, w = tid >> 6, lane = tid & 63;
  int l16 = lane & 15, lq = lane >> 4;
  __shared__ __align__(16) short Ks[128 * 128];   // 32 KB, [key][d] chunk16 ^ l16 swizzle
  __shared__ __align__(16) short Vs[128 * 128];   // 32 KB, [d][key]
  short* pbuf = Ks + w * 2176;                    // 16 x 136, aliased after barrier C
  const short* qh = q + (long)h * SQ * HD;
  const short* kg = k + (long)g * SQ * HD;
  const short* vg = vT + (long)g * HD * SQ;
  int qtA = pair, qtB = 31 - pair;
  int ktmaxA = qtA >> 1, ktmaxB = qtB >> 1;
  const float sc = 0.08838834764831845f * 1.4426950408889634f;

  bf16x8 aqA[4], aqB[4];
#pragma unroll
  for (int kk = 0; kk < 4; ++kk) {
    aqA[kk] = *(const bf16x8*)&qh[(long)(qtA * 64 + w * 16 + l16) * HD + kk * 32 + lq * 8];
    aqB[kk] = *(const bf16x8*)&qh[(long)(qtB * 64 + w * 16 + l16) * HD + kk * 32 + lq * 8];
  }
  float mA[4], lA[4], mB[4], lB[4];
  f32x4 accA[8] = {}, accB[8] = {};
#pragma unroll
  for (int r = 0; r < 4; ++r) { mA[r] = NEG_INF; lA[r] = 0.f; mB[r] = NEG_INF; lB[r] = 0.f; }
  int qrowA = qtA * 64 + w * 16 + lq * 4;
  int qrowB = qtB * 64 + w * 16 + lq * 4;
  float pA[32], pB[32];

  for (int kt = 0; kt <= ktmaxB; ++kt) {
    __syncthreads();                              // A: prev iter LDS fully consumed
#pragma unroll
    for (int j = 0; j < 8; ++j) {
      int call = w * 8 + j;
      int r = call * 4 + (lane >> 4);
      int chk = (lane & 15) ^ (r & 15);
      gl2lds(&kg[(long)(kt * 128 + r) * HD + chk * 8], &Ks[call * 512]);
      gl2lds(&vg[(long)r * SQ + kt * 128 + chk * 8], &Vs[call * 512]);
    }
    __syncthreads();                              // B: stage complete
    bool doA = (kt <= ktmaxA);
    int nbB = 8, nbA = 8;
    if (kt == ktmaxB && !(qtB & 1)) nbB = 4;
    if (kt == ktmaxA && !(qtA & 1)) nbA = 4;
    if (kt == ktmaxB) {
      if (nbB == 8) score_tile<8, true>(Ks, aqB, pB, mB, lB, accB, kt * 128, qrowB, l16, lq, sc);
      else          score_tile<4, true>(Ks, aqB, pB, mB, lB, accB, kt * 128, qrowB, l16, lq, sc);
    } else          score_tile<8, false>(Ks, aqB, pB, mB, lB, accB, kt * 128, qrowB, l16, lq, sc);
    if (doA) {
      if (kt == ktmaxA) {
        if (nbA == 8) score_tile<8, true>(Ks, aqA, pA, mA, lA, accA, kt * 128, qrowA, l16, lq, sc);
        else          score_tile<4, true>(Ks, aqA, pA, mA, lA, accA, kt * 128, qrowA, l16, lq, sc);
      } else          score_tile<8, false>(Ks, aqA, pA, mA, lA, accA, kt * 128, qrowA, l16, lq, sc);
    }
    __syncthreads();                              // C: all Ks reads done, pbuf may alias
    if (nbB == 8) pv_tile<8>(pbuf, Vs, pB, accB, l16, lq);
    else          pv_tile<4>(pbuf, Vs, pB, accB, l16, lq);
    if (doA) {
      if (nbA == 8) pv_tile<8>(pbuf, Vs, pA, accA, l16, lq);
      else          pv_tile<4>(pbuf, Vs, pA, accA, l16, lq);
    }
  }
#pragma unroll
  for (int n = 0; n < 8; ++n)
#pragma unroll
    for (int r = 0; r < 4; ++r) {
      ctx[(long)(qrowA + r) * (NH * HD) + h * HD + n * 16 + l16] = f2bf(accA[n][r] / lA[r]);
      ctx[(long)(qrowB + r) * (NH * HD) + h * HD + n * 16 + l16] = f2bf(accB[n][r] / lB[r]);
    }
}

// ---------------- workspace layout ----------------
// xb    [0, 16.7MB)          dead after gemm_qkv; ctx aliases it
// wqkvt [16.7MB, 67.1MB)     dead after gemm_qkv
// wot   [67.1MB, 100.7MB)
// qr    [100.7MB, 117.4MB)
// kr    [117.4MB, 121.6MB)
// vt    [121.6MB, 125.8MB)
#define XB_OFF     0L
#define CTX_OFF    0L
#define WQKVT_OFF  16777216L
#define WOT_OFF    67108864L
#define QR_OFF     100663296L
#define KR_OFF     117440512L
#define VT_OFF     121634816L

extern "C" void kernel_launch(void* const* d_in, const int* in_sizes, int n_in,
                              void* d_out, int out_size, void* d_ws, size_t ws_size,
                              hipStream_t stream) {
  const float* x    = (const float*)d_in[0];
  const float* cosb = (const float*)d_in[2];
  const float* sinb = (const float*)d_in[3];
  const float* Wq   = (const float*)d_in[4];
  const float* Wk   = (const float*)d_in[5];
  const float* Wv   = (const float*)d_in[6];
  const float* Wo   = (const float*)d_in[7];
  const float* qnw  = (const float*)d_in[8];
  const float* qnb  = (const float*)d_in[9];
  const float* knw  = (const float*)d_in[10];
  const float* knb  = (const float*)d_in[11];

  char* ws = (char*)d_ws;
  short* xb    = (short*)(ws + XB_OFF);
  short* ctx   = (short*)(ws + CTX_OFF);
  short* wqkvt = (short*)(ws + WQKVT_OFF);
  short* wot   = (short*)(ws + WOT_OFF);
  short* qr    = (short*)(ws + QR_OFF);
  short* krp   = (short*)(ws + KR_OFF);
  short* vt    = (short*)(ws + VT_OFF);

  cvt_bf16<<<8192, 256, 0, stream>>>(x, xb, (long)SQ * DIN);
  transpose_cvt<<<dim3(64, 64, 1), 256, 0, stream>>>(Wq, 4096, 0L, wqkvt, 4096, 0L);
  transpose_cvt<<<dim3(16, 64, 1), 256, 0, stream>>>(Wk, 1024, 0L, wqkvt + (long)4096 * 4096, 4096, 0L);
  transpose_cvt<<<dim3(16, 64, 1), 256, 0, stream>>>(Wv, 1024, 0L, wqkvt + (long)5120 * 4096, 4096, 0L);
  transpose_cvt<<<dim3(64, 64, 1), 256, 0, stream>>>(Wo, 4096, 0L, wot, 4096, 0L);
  gemm_qkv<<<dim3(NQKV / BN, SQ / BM), 256, 0, stream>>>(xb, wqkvt, cosb, sinb,
                                                         qnw, qnb, knw, knb, qr, krp, vt);
  attn<<<dim3(16, NH), 256, 0, stream>>>(qr, krp, vt, ctx);
  gemm_bf16<<<dim3(DIN / BN, SQ / BM), 256, 0, stream>>>(ctx, wot, (float*)d_out, SQ, DIN, DIN);
}